// Round 1
// baseline (624.244 us; speedup 1.0000x reference)
//
#include <hip/hip_runtime.h>
#include <stdint.h>

#define B_ 16
#define N_ 25200
#define NC_ 80
#define TOPK 2048
#define MAXDET 300
#define CONF_T 0.25f
#define IOU_T 0.45f
#define MAX_WH_ 4096.0f
#define NBINS 4096
#define CAP 4096
#define MROWS 2064  // 2048 + 16 prefetch pad rows

// ---------------- K1: per-anchor score/class ----------------
__global__ __launch_bounds__(256) void k_score(const float* __restrict__ pred,
                                               uint32_t* __restrict__ keys,
                                               uint32_t* __restrict__ cls) {
  int gid = blockIdx.x * 256 + threadIdx.x;
  if (gid >= B_ * N_) return;
  const float* p = pred + (size_t)gid * 85;
  float obj = p[4];
  float best = -1.0f;
  int bj = 0;
#pragma unroll 8
  for (int c = 0; c < NC_; ++c) {
    float v = p[5 + c] * obj;  // plain mul, matches ref exactly
    if (v > best) { best = v; bj = c; }  // strict > => first-max like argmax
  }
  bool valid = (obj > CONF_T) && (best > CONF_T);
  float score = valid ? best : 0.0f;
  keys[gid] = __float_as_uint(score);  // score >= 0: bits are order-isomorphic
  cls[gid] = (uint32_t)bj;
}

// ---------------- K2: exact top-2048 per batch (one block/batch) ----------------
__global__ __launch_bounds__(1024) void k_topk(const uint32_t* __restrict__ keys,
                                               uint32_t* __restrict__ topk_idx,
                                               float* __restrict__ topk_score) {
  __shared__ uint32_t hist[NBINS];
  __shared__ unsigned long long cand[CAP];
  __shared__ uint32_t s_b1, s_need2, s_b2, s_cnt;
  const int b = blockIdx.x;
  const int tid = threadIdx.x;
  const uint32_t* kb = keys + (size_t)b * N_;

  // level-1 histogram on bits [30:19]
  for (int i = tid; i < NBINS; i += 1024) hist[i] = 0;
  __syncthreads();
  for (int n = tid; n < N_; n += 1024) atomicAdd(&hist[kb[n] >> 19], 1u);
  __syncthreads();
  if (tid == 0) {
    uint32_t cum = 0; int b1 = 0;
    for (int i = NBINS - 1; i >= 0; --i) {
      cum += hist[i];
      if (cum >= TOPK) { b1 = i; break; }
    }
    s_b1 = (uint32_t)b1;
    s_need2 = TOPK - (cum - hist[b1]);  // >=1, <= hist[b1]
  }
  __syncthreads();
  const uint32_t b1 = s_b1, need2 = s_need2;

  // level-2 histogram on bits [18:7] within bin b1
  for (int i = tid; i < NBINS; i += 1024) hist[i] = 0;
  __syncthreads();
  for (int n = tid; n < N_; n += 1024) {
    uint32_t k = kb[n];
    if ((k >> 19) == b1) atomicAdd(&hist[(k >> 7) & 4095u], 1u);
  }
  __syncthreads();
  if (tid == 0) {
    uint32_t cum = 0; int b2 = 0;
    for (int i = NBINS - 1; i >= 0; --i) {
      cum += hist[i];
      if (cum >= need2) { b2 = i; break; }
    }
    s_b2 = (uint32_t)b2;
    s_cnt = 0;
  }
  __syncthreads();
  const uint32_t b2 = s_b2;

  // collect candidates (exact superset of true top-2048)
  for (int n = tid; n < N_; n += 1024) {
    uint32_t k = kb[n];
    uint32_t bin = k >> 19;
    bool sel = (bin > b1) || (bin == b1 && ((k >> 7) & 4095u) >= b2);
    if (sel) {
      uint32_t p = atomicAdd(&s_cnt, 1u);
      if (p < CAP)
        cand[p] = ((unsigned long long)k << 32) | (uint32_t)(~(uint32_t)n);
    }
  }
  __syncthreads();
  uint32_t cnt = s_cnt < CAP ? s_cnt : CAP;
  for (int i = (int)cnt + tid; i < CAP; i += 1024) cand[i] = 0ull;
  __syncthreads();

  // bitonic sort, descending, S = CAP = 4096
  for (unsigned k = 2; k <= CAP; k <<= 1) {
    for (unsigned j = k >> 1; j > 0; j >>= 1) {
      for (unsigned i = tid; i < CAP; i += 1024) {
        unsigned ixj = i ^ j;
        if (ixj > i) {
          unsigned long long a = cand[i], c = cand[ixj];
          bool desc = ((i & k) == 0);
          if (desc ? (a < c) : (a > c)) { cand[i] = c; cand[ixj] = a; }
        }
      }
      __syncthreads();
    }
  }

  for (int r = tid; r < TOPK; r += 1024) {
    unsigned long long key = cand[r];
    uint32_t idx = ~((uint32_t)(key & 0xFFFFFFFFull));
    topk_idx[(size_t)b * TOPK + r] = idx;
    topk_score[(size_t)b * TOPK + r] = __uint_as_float((uint32_t)(key >> 32));
  }
}

// ---------------- K3: gather boxes for selected ----------------
__global__ __launch_bounds__(256) void k_prep(const float* __restrict__ pred,
                                              const uint32_t* __restrict__ cls,
                                              const uint32_t* __restrict__ topk_idx,
                                              float4* __restrict__ box4,
                                              float4* __restrict__ obox4,
                                              float* __restrict__ clsf) {
  int gid = blockIdx.x * 256 + threadIdx.x;  // b*TOPK + r
  if (gid >= B_ * TOPK) return;
  int b = gid >> 11;
  uint32_t idx = topk_idx[gid];
  const float* p = pred + ((size_t)b * N_ + idx) * 85;
  float x = p[0], y = p[1], w = p[2], h = p[3];
  float hw = w * 0.5f, hh = h * 0.5f;  // exact (pow2 scale)
  float bx0 = x - hw, by0 = y - hh, bx1 = x + hw, by1 = y + hh;
  float jf = (float)cls[(size_t)b * N_ + idx];
  float off = jf * MAX_WH_;  // exact
  box4[gid] = make_float4(bx0, by0, bx1, by1);
  obox4[gid] = make_float4(bx0 + off, by0 + off, bx1 + off, by1 + off);
  clsf[gid] = jf;
}

// ---------------- K4: pairwise suppression bitmask ----------------
__global__ __launch_bounds__(256) void k_iou(const float4* __restrict__ obox4,
                                             uint32_t* __restrict__ M) {
  __shared__ float4 ob[TOPK];
  const int b = blockIdx.x >> 5;   // 32 blocks per batch
  const int ig = blockIdx.x & 31;
  const int tid = threadIdx.x;
  for (int t = tid; t < TOPK; t += 256) ob[t] = obox4[(size_t)b * TOPK + t];
  __syncthreads();
  const int i = ig * 64 + (tid >> 2);
  const int jc = tid & 3;
  float4 bi = ob[i];
  float a1 = __fmul_rn(__fsub_rn(bi.z, bi.x), __fsub_rn(bi.w, bi.y));
  uint32_t* Mrow = M + ((size_t)b * MROWS + i) * 64 + jc * 16;
  for (int w = 0; w < 16; ++w) {
    uint32_t bits = 0;
    int jbase = jc * 512 + w * 32;
#pragma unroll 8
    for (int jj = 0; jj < 32; ++jj) {
      float4 bj = ob[jbase + jj];
      float a2 = __fmul_rn(__fsub_rn(bj.z, bj.x), __fsub_rn(bj.w, bj.y));
      float ltx = fmaxf(bi.x, bj.x), lty = fmaxf(bi.y, bj.y);
      float rbx = fminf(bi.z, bj.z), rby = fminf(bi.w, bj.w);
      float dx = fmaxf(__fsub_rn(rbx, ltx), 0.0f);
      float dy = fmaxf(__fsub_rn(rby, lty), 0.0f);
      float inter = __fmul_rn(dx, dy);
      float uni = __fsub_rn(__fadd_rn(a1, a2), inter);  // forbid FMA contraction
      float iou = __fdiv_rn(inter, uni);
      bits |= (iou > IOU_T) ? (1u << jj) : 0u;
    }
    Mrow[w] = bits;
  }
}

// ---------------- K5: sequential greedy sweep (1 wave/batch) ----------------
__global__ __launch_bounds__(64) void k_nms(const uint32_t* __restrict__ M,
                                            const float* __restrict__ topk_score,
                                            uint32_t* __restrict__ keepmask,
                                            float* __restrict__ out_counts) {
  const int b = blockIdx.x;
  const int l = threadIdx.x;  // 0..63, owns keep word l (j = l*32 .. l*32+31)
  uint32_t keep = 0;
#pragma unroll 8
  for (int jj = 0; jj < 32; ++jj) {
    float s = topk_score[(size_t)b * TOPK + l * 32 + jj];
    keep |= (s > CONF_T ? 1u : 0u) << jj;
  }
  uint32_t kept = 0;
  const uint32_t* Mb = M + (size_t)b * MROWS * 64;

  uint32_t buf[16];
#pragma unroll
  for (int t = 0; t < 16; ++t) buf[t] = Mb[(size_t)t * 64 + l];

  for (int g = 0; g < TOPK / 16; ++g) {
    uint32_t nxt[16];
#pragma unroll
    for (int t = 0; t < 16; ++t)
      nxt[t] = Mb[((size_t)(g + 1) * 16 + t) * 64 + l];  // pad rows make this safe
#pragma unroll
    for (int t = 0; t < 16; ++t) {
      int i = g * 16 + t;
      int owner = i >> 5;
      uint32_t kw = (uint32_t)__shfl((int)keep, owner, 64);
      if ((kw >> (i & 31)) & 1u) {
        if (l == owner) kept |= 1u << (i & 31);
        keep &= ~buf[t];
      }
    }
#pragma unroll
    for (int t = 0; t < 16; ++t) buf[t] = nxt[t];
  }

  keepmask[b * 64 + l] = kept;
  int c = __popc(kept);
  for (int off = 32; off > 0; off >>= 1) c += __shfl_down(c, off, 64);
  if (l == 0) out_counts[b] = (float)c;
}

// ---------------- K6: emit up to 300 rows ----------------
__global__ __launch_bounds__(64) void k_out(const uint32_t* __restrict__ keepmask,
                                            const float4* __restrict__ box4,
                                            const float* __restrict__ topk_score,
                                            const float* __restrict__ clsf,
                                            float* __restrict__ out) {
  const int b = blockIdx.x;
  const int l = threadIdx.x;
  float* ob = out + (size_t)b * MAXDET * 6;
  for (int t = l; t < MAXDET * 6; t += 64) ob[t] = 0.0f;
  __syncthreads();
  uint32_t w = keepmask[b * 64 + l];
  int pc = __popc(w);
  int pre = pc;
  for (int off = 1; off < 64; off <<= 1) {
    int v = __shfl_up(pre, off, 64);
    if (l >= off) pre += v;
  }
  int r = pre - pc;  // exclusive prefix of kept counts
  for (int jj = 0; jj < 32; ++jj) {
    if ((w >> jj) & 1u) {
      if (r < MAXDET) {
        int k = l * 32 + jj;
        float4 bx = box4[(size_t)b * TOPK + k];
        float sc = topk_score[(size_t)b * TOPK + k];
        float cf = clsf[(size_t)b * TOPK + k];
        float* row = ob + (size_t)r * 6;
        row[0] = bx.x; row[1] = bx.y; row[2] = bx.z; row[3] = bx.w;
        row[4] = sc;   row[5] = cf;
      }
      ++r;
    }
  }
}

extern "C" void kernel_launch(void* const* d_in, const int* in_sizes, int n_in,
                              void* d_out, int out_size, void* d_ws, size_t ws_size,
                              hipStream_t stream) {
  const float* pred = (const float*)d_in[0];
  float* out = (float*)d_out;

  char* ws = (char*)d_ws;
  size_t off = 0;
  uint32_t* keys = (uint32_t*)(ws + off); off += (size_t)B_ * N_ * 4;            // 1,612,800
  uint32_t* cls = (uint32_t*)(ws + off);  off += (size_t)B_ * N_ * 4;            // 1,612,800
  uint32_t* topk_idx = (uint32_t*)(ws + off); off += (size_t)B_ * TOPK * 4;      // 131,072
  float* topk_score = (float*)(ws + off);  off += (size_t)B_ * TOPK * 4;         // 131,072
  float4* box4 = (float4*)(ws + off);      off += (size_t)B_ * TOPK * 16;        // 524,288
  float4* obox4 = (float4*)(ws + off);     off += (size_t)B_ * TOPK * 16;        // 524,288
  float* clsf = (float*)(ws + off);        off += (size_t)B_ * TOPK * 4;         // 131,072
  uint32_t* keepmask = (uint32_t*)(ws + off); off += (size_t)B_ * 64 * 4;        // 4,096
  uint32_t* M = (uint32_t*)(ws + off);     off += (size_t)B_ * MROWS * 64 * 4;   // 8,454,144

  (void)in_sizes; (void)n_in; (void)out_size; (void)ws_size;

  k_score<<<(B_ * N_ + 255) / 256, 256, 0, stream>>>(pred, keys, cls);
  k_topk<<<B_, 1024, 0, stream>>>(keys, topk_idx, topk_score);
  k_prep<<<(B_ * TOPK + 255) / 256, 256, 0, stream>>>(pred, cls, topk_idx, box4, obox4, clsf);
  k_iou<<<B_ * 32, 256, 0, stream>>>(obox4, M);
  k_nms<<<B_, 64, 0, stream>>>(M, topk_score, keepmask, out + (size_t)B_ * MAXDET * 6);
  k_out<<<B_, 64, 0, stream>>>(keepmask, box4, topk_score, clsf, out);
}